// Round 8
// baseline (394.605 us; speedup 1.0000x reference)
//
#include <hip/hip_runtime.h>
#include <math.h>

#define Nn 50000
#define Ee 600000
#define Bg 128      // batches (graphs)
#define Hd 128      // hidden dim
#define Kt 30       // sortpool K
#define CO 32       // conv out channels
#define KW 5        // conv kernel
#define LOUT 26     // K - KW + 1
#define CAP 2048    // per-batch node cap for topk LDS (max real count ~460)
#define SCB 196     // ceil(50000/256) scan blocks
#define MMB 782     // mmx blocks = ceil(50000/64)

typedef float v2f __attribute__((ext_vector_type(2)));
typedef short bf16x8 __attribute__((ext_vector_type(8)));
typedef float f32x4 __attribute__((ext_vector_type(4)));

// bf16 round-to-nearest-even helpers (branchless, finite inputs)
__device__ __forceinline__ unsigned short bfr(float v) {
    unsigned u = __builtin_bit_cast(unsigned, v);
    unsigned r = (u + 0x7FFFu + ((u >> 16) & 1u)) >> 16;
    return (unsigned short)r;
}
__device__ __forceinline__ float bff(unsigned short h) {
    unsigned u = ((unsigned)h) << 16;
    return __builtin_bit_cast(float, u);
}

// ---- count + batch starts + conv_w transpose + W 3-way split/pack ----------
// deg_i/cnt/bstart pre-set to -1 (0xFF memset). deg_i[c] ends at (#incoming - 1).
__global__ void countpack_kernel(const int* __restrict__ ei, const int* __restrict__ batch,
                            int* __restrict__ deg_i, int* __restrict__ bstart,
                            const float* __restrict__ conv_w, float* __restrict__ wT2,
                            const float* __restrict__ W0, const float* __restrict__ W1,
                            const float* __restrict__ W2,
                            ushort* __restrict__ Bph, ushort* __restrict__ Bpm,
                            ushort* __restrict__ Bpl) {
    int i = blockIdx.x * 256 + threadIdx.x;
    if (i < Ee) atomicAdd(&deg_i[ei[Ee + i]], 1);       // col = edge_index[1]
    if (i < Nn) {
        int b = batch[i];
        if (i == 0) bstart[b] = 0;
        else if (batch[i - 1] != b) bstart[b] = i;
    }
    if (i == 0) bstart[Bg] = Nn;
    if (i < CO * KW * Hd) {                     // wT2[o][k][ci] = conv_w[o][ci][k]
        int ci = i & 127;
        int r = i >> 7;          // o*KW + k
        int o = r / KW, k = r - o * KW;
        wT2[i] = conv_w[((size_t)o * Hd + ci) * KW + k];
    }
    if (i < 3 * 2048) {                          // W split+pack, B-fragment layout
        int l = i >> 11;
        int r = i & 2047;
        int kc = r >> 9;
        int n = (r >> 6) & 7;
        int lane = r & 63;
        int m = lane & 15, kq = lane >> 4;
        const float* W = (l == 0) ? W0 : (l == 1) ? W1 : W2;
        int col = n * 16 + m;
        size_t off = ((size_t)l * 2048 + (size_t)((kc * 8 + n) * 64 + lane)) * 8;
#pragma unroll
        for (int j = 0; j < 8; ++j) {
            float v = W[(size_t)(kc * 32 + kq * 8 + j) * Hd + col];
            unsigned short h = bfr(v);
            float r1 = v - bff(h);
            unsigned short mid = bfr(r1);
            Bph[off + j] = h;
            Bpm[off + j] = mid;
            Bpl[off + j] = bfr(r1 - bff(mid));
        }
    }
}

// ---- single scan dispatch: per-block direct offset sum + local scan + dinv --
__global__ __launch_bounds__(256) void scanBC2_kernel(const int* __restrict__ deg_i,
                            int* __restrict__ row_ptr, float* __restrict__ dinv,
                            int* __restrict__ bstart) {
    __shared__ int ls[256];
    __shared__ int boffS;
    int tid = threadIdx.x;
    int b = blockIdx.x;
    int s = 0;
    for (int k = 0; k < b; ++k)                 // j = k*256+tid < b*256 <= 49920 < Nn
        s += deg_i[k * 256 + tid] + 1;
    ls[tid] = s;
    __syncthreads();
    for (int off = 128; off > 0; off >>= 1) {
        if (tid < off) ls[tid] += ls[tid + off];
        __syncthreads();
    }
    if (tid == 0) boffS = ls[0];
    __syncthreads();
    int boff = boffS;
    int i = b * 256 + tid;
    int v2 = 0;
    if (i < Nn) {
        int raw = deg_i[i];
        v2 = raw + 1;                           // CSR row length (= #incoming)
        dinv[i] = 1.0f / sqrtf((float)(raw + 2));  // degree incl. self loop
    }
    ls[tid] = v2;
    __syncthreads();
    for (int off = 1; off < 256; off <<= 1) {
        int t = (tid >= off) ? ls[tid - off] : 0;
        __syncthreads();
        ls[tid] += t;
        __syncthreads();
    }
    if (i < Nn) row_ptr[i + 1] = ls[tid] + boff;
    if (i == 0) row_ptr[0] = 0;
    if (b == 0 && tid == 0) {   // empty batches inherit next start (batch sorted)
        for (int bb = Bg - 1; bb >= 0; --bb)
            if (bstart[bb] == -1) bstart[bb] = bstart[bb + 1];
    }
}

// ---------------- MFMA matmul body (used by mmxfill, layer 0) -----------------
// A-tile (contiguous 32KB) staged COALESCED into padded LDS [64][132]; fragment
// reads from LDS. 3-way split-bf16 (near-fp32).
__device__ __forceinline__ void mmx_body(int bid, int tid,
                            const float* __restrict__ Hin,
                            const ushort* __restrict__ Bph, const ushort* __restrict__ Bpm,
                            const ushort* __restrict__ Bpl,
                            const float* __restrict__ dinv, float* __restrict__ hw) {
    __shared__ __align__(16) float At[64][132];
    int w = tid >> 6, lane = tid & 63;
    int m = lane & 15, kq = lane >> 4;
    // ---- coalesced stage: rows bid*64.. (32 KB contiguous) -> LDS ----
    {
        const f32x4* g4 = (const f32x4*)(Hin + (size_t)bid * 64 * Hd);
        int rowsLeft = Nn - bid * 64;            // < 64 only for the last block
#pragma unroll
        for (int i = 0; i < 8; ++i) {
            int f = i * 256 + tid;               // float4 index in tile
            int r = f >> 5, c4 = f & 31;         // 32 float4 per row
            f32x4 v = (f32x4)0.f;
            if (r < rowsLeft) v = g4[f];
            *(f32x4*)&At[r][c4 * 4] = v;
        }
    }
    __syncthreads();
    const float* arow = &At[w * 16 + m][0];
    f32x4 acc[8];
#pragma unroll
    for (int n = 0; n < 8; ++n) acc[n] = (f32x4)0.f;
#pragma unroll
    for (int kc = 0; kc < 4; ++kc) {
        bf16x8 a0, a1, a2;
        float av[8];
        *(f32x4*)&av[0] = *(const f32x4*)(arow + kc * 32 + kq * 8);
        *(f32x4*)&av[4] = *(const f32x4*)(arow + kc * 32 + kq * 8 + 4);
#pragma unroll
        for (int j = 0; j < 8; ++j) {
            unsigned short h = bfr(av[j]);
            float r1 = av[j] - bff(h);
            unsigned short mid = bfr(r1);
            a0[j] = (short)h;
            a1[j] = (short)mid;
            a2[j] = (short)bfr(r1 - bff(mid));
        }
        const ushort* bhp = Bph + (size_t)((kc * 8) * 64 + lane) * 8;
        const ushort* bmp = Bpm + (size_t)((kc * 8) * 64 + lane) * 8;
        const ushort* blp = Bpl + (size_t)((kc * 8) * 64 + lane) * 8;
#pragma unroll
        for (int n = 0; n < 8; ++n) {
            bf16x8 b0 = *(const bf16x8*)(bhp + (size_t)n * 64 * 8);
            bf16x8 b1 = *(const bf16x8*)(bmp + (size_t)n * 64 * 8);
            bf16x8 b2 = *(const bf16x8*)(blp + (size_t)n * 64 * 8);
            acc[n] = __builtin_amdgcn_mfma_f32_16x16x32_bf16(a0, b0, acc[n], 0, 0, 0);
            acc[n] = __builtin_amdgcn_mfma_f32_16x16x32_bf16(a1, b0, acc[n], 0, 0, 0);
            acc[n] = __builtin_amdgcn_mfma_f32_16x16x32_bf16(a0, b1, acc[n], 0, 0, 0);
            acc[n] = __builtin_amdgcn_mfma_f32_16x16x32_bf16(a1, b1, acc[n], 0, 0, 0);
            acc[n] = __builtin_amdgcn_mfma_f32_16x16x32_bf16(a2, b0, acc[n], 0, 0, 0);
            acc[n] = __builtin_amdgcn_mfma_f32_16x16x32_bf16(a0, b2, acc[n], 0, 0, 0);
        }
    }
    int rbase = bid * 64 + w * 16 + kq * 4;
#pragma unroll
    for (int reg = 0; reg < 4; ++reg) {
        int r = rbase + reg;
        if (r < Nn) {
            float s = dinv[r];
#pragma unroll
            for (int n = 0; n < 8; ++n)
                hw[(size_t)r * Hd + n * 16 + m] = acc[n][reg] * s;
        }
    }
}

// ---- merged layer-0 matmul + CSR fill (independent work, block-range split) --
__global__ __launch_bounds__(256) void mmxfill_kernel(const float* __restrict__ Hin,
                            const ushort* __restrict__ Bph, const ushort* __restrict__ Bpm,
                            const ushort* __restrict__ Bpl,
                            const float* __restrict__ dinv, float* __restrict__ hw,
                            const int* __restrict__ ei, const int* __restrict__ row_ptr,
                            int* __restrict__ cnt, int* __restrict__ csr_src) {
    if (blockIdx.x < MMB) {
        mmx_body(blockIdx.x, threadIdx.x, Hin, Bph, Bpm, Bpl, dinv, hw);
    } else {
        int e = (blockIdx.x - MMB) * 256 + threadIdx.x;
        if (e < Ee) {
            int c = ei[Ee + e];
            int r = ei[e];
            int p = row_ptr[c] + atomicAdd(&cnt[c], 1) + 1;   // cnt starts at -1
            csr_src[p] = r;
        }
    }
}

// ---- FUSED agg(layer l) + matmul(layer l+1), 1024-thread / 16-wave tile -----
// Gather phase keeps agg_kernel's PROVEN engine: 1 wave per node, coalesced
// v2f 512B row gathers, 8-deep ILP, identical 8/4/1 accumulator tree (bitwise
// same h). 16 waves x 4 nodes = 64-row LDS tile; one barrier; matmul with
// wave = (row-group, n-pair) split. 2 blocks/CU (32 waves) by thread limit;
// __launch_bounds__(1024,8) caps VGPR at 64 to keep both blocks resident.
__global__ __launch_bounds__(1024, 8) void aggmm_kernel(const float* __restrict__ hwin,
                            const int* __restrict__ row_ptr, const int* __restrict__ csr_src,
                            const float* __restrict__ dinv, const float* __restrict__ bias,
                            const ushort* __restrict__ Bph, const ushort* __restrict__ Bpm,
                            const ushort* __restrict__ Bpl,
                            float* __restrict__ hwout, float* __restrict__ col127) {
    __shared__ __align__(16) float At[64][132];
    int tid = threadIdx.x;
    int w = tid >> 6, lane = tid & 63;
    int bid = blockIdx.x;
    const v2f* hw2 = (const v2f*)hwin;
    v2f bv = ((const v2f*)bias)[lane];
    // ---- phase 1: wave w aggregates nodes bid*64 + w*4 .. +3 ----
#pragma unroll
    for (int t = 0; t < 4; ++t) {
        int rl = w * 4 + t;
        int node = bid * 64 + rl;
        v2f o = (v2f)0.f;
        if (node < Nn) {
            v2f a0 = hw2[(size_t)node * 64 + lane];   // self loop (pre-scaled by dinv[src])
            v2f a1 = 0.f, a2 = 0.f, a3 = 0.f;
            v2f a4 = 0.f, a5 = 0.f, a6 = 0.f, a7 = 0.f;
            int e0 = row_ptr[node], e1 = row_ptr[node + 1];
            int e = e0;
            for (; e + 7 < e1; e += 8) {
                int s0 = __builtin_nontemporal_load(csr_src + e);
                int s1 = __builtin_nontemporal_load(csr_src + e + 1);
                int s2 = __builtin_nontemporal_load(csr_src + e + 2);
                int s3 = __builtin_nontemporal_load(csr_src + e + 3);
                int s4 = __builtin_nontemporal_load(csr_src + e + 4);
                int s5 = __builtin_nontemporal_load(csr_src + e + 5);
                int s6 = __builtin_nontemporal_load(csr_src + e + 6);
                int s7 = __builtin_nontemporal_load(csr_src + e + 7);
                a0 += hw2[(size_t)s0 * 64 + lane];
                a1 += hw2[(size_t)s1 * 64 + lane];
                a2 += hw2[(size_t)s2 * 64 + lane];
                a3 += hw2[(size_t)s3 * 64 + lane];
                a4 += hw2[(size_t)s4 * 64 + lane];
                a5 += hw2[(size_t)s5 * 64 + lane];
                a6 += hw2[(size_t)s6 * 64 + lane];
                a7 += hw2[(size_t)s7 * 64 + lane];
            }
            if (e + 3 < e1) {
                int s0 = __builtin_nontemporal_load(csr_src + e);
                int s1 = __builtin_nontemporal_load(csr_src + e + 1);
                int s2 = __builtin_nontemporal_load(csr_src + e + 2);
                int s3 = __builtin_nontemporal_load(csr_src + e + 3);
                a4 += hw2[(size_t)s0 * 64 + lane];
                a5 += hw2[(size_t)s1 * 64 + lane];
                a6 += hw2[(size_t)s2 * 64 + lane];
                a7 += hw2[(size_t)s3 * 64 + lane];
                e += 4;
            }
            for (; e < e1; ++e) {
                int s0 = __builtin_nontemporal_load(csr_src + e);
                a0 += hw2[(size_t)s0 * 64 + lane];
            }
            v2f acc = ((a0 + a1) + (a2 + a3)) + ((a4 + a5) + (a6 + a7));
            float d = dinv[node];
            o.x = fmaxf(fmaf(d, acc.x, bv.x), 0.f);
            o.y = fmaxf(fmaf(d, acc.y, bv.y), 0.f);
        }
        *(v2f*)&At[rl][lane * 2] = o;
    }
    __syncthreads();
    // ---- phase 2: matmul; wave = (row-group g, n-pair n0) ----
    int g = w >> 2, n0 = (w & 3) * 2;
    int m = lane & 15, kq = lane >> 4;
    const float* arow = &At[g * 16 + m][0];
    f32x4 acc0 = (f32x4)0.f, acc1 = (f32x4)0.f;
#pragma unroll
    for (int kc = 0; kc < 4; ++kc) {
        bf16x8 a0, a1, a2;
        float av[8];
        *(f32x4*)&av[0] = *(const f32x4*)(arow + kc * 32 + kq * 8);
        *(f32x4*)&av[4] = *(const f32x4*)(arow + kc * 32 + kq * 8 + 4);
#pragma unroll
        for (int j = 0; j < 8; ++j) {
            unsigned short h = bfr(av[j]);
            float r1 = av[j] - bff(h);
            unsigned short mid = bfr(r1);
            a0[j] = (short)h;
            a1[j] = (short)mid;
            a2[j] = (short)bfr(r1 - bff(mid));
        }
        const ushort* bhp = Bph + (size_t)((kc * 8 + n0) * 64 + lane) * 8;
        const ushort* bmp = Bpm + (size_t)((kc * 8 + n0) * 64 + lane) * 8;
        const ushort* blp = Bpl + (size_t)((kc * 8 + n0) * 64 + lane) * 8;
        {
            bf16x8 b0 = *(const bf16x8*)bhp;
            bf16x8 b1 = *(const bf16x8*)bmp;
            bf16x8 b2 = *(const bf16x8*)blp;
            acc0 = __builtin_amdgcn_mfma_f32_16x16x32_bf16(a0, b0, acc0, 0, 0, 0);
            acc0 = __builtin_amdgcn_mfma_f32_16x16x32_bf16(a1, b0, acc0, 0, 0, 0);
            acc0 = __builtin_amdgcn_mfma_f32_16x16x32_bf16(a0, b1, acc0, 0, 0, 0);
            acc0 = __builtin_amdgcn_mfma_f32_16x16x32_bf16(a1, b1, acc0, 0, 0, 0);
            acc0 = __builtin_amdgcn_mfma_f32_16x16x32_bf16(a2, b0, acc0, 0, 0, 0);
            acc0 = __builtin_amdgcn_mfma_f32_16x16x32_bf16(a0, b2, acc0, 0, 0, 0);
        }
        {
            bf16x8 b0 = *(const bf16x8*)(bhp + 64 * 8);
            bf16x8 b1 = *(const bf16x8*)(bmp + 64 * 8);
            bf16x8 b2 = *(const bf16x8*)(blp + 64 * 8);
            acc1 = __builtin_amdgcn_mfma_f32_16x16x32_bf16(a0, b0, acc1, 0, 0, 0);
            acc1 = __builtin_amdgcn_mfma_f32_16x16x32_bf16(a1, b0, acc1, 0, 0, 0);
            acc1 = __builtin_amdgcn_mfma_f32_16x16x32_bf16(a0, b1, acc1, 0, 0, 0);
            acc1 = __builtin_amdgcn_mfma_f32_16x16x32_bf16(a1, b1, acc1, 0, 0, 0);
            acc1 = __builtin_amdgcn_mfma_f32_16x16x32_bf16(a2, b0, acc1, 0, 0, 0);
            acc1 = __builtin_amdgcn_mfma_f32_16x16x32_bf16(a0, b2, acc1, 0, 0, 0);
        }
    }
    int rbase = bid * 64 + g * 16 + kq * 4;
#pragma unroll
    for (int reg = 0; reg < 4; ++reg) {
        int r = rbase + reg;
        if (r < Nn) {
            float s = dinv[r];
            hwout[(size_t)r * Hd + n0 * 16 + m] = acc0[reg] * s;
            hwout[(size_t)r * Hd + (n0 + 1) * 16 + m] = acc1[reg] * s;
            if (n0 == 6 && m == 15) col127[r] = acc1[reg] * s;  // = hw[r*128+127]
        }
    }
}

// ---------------- fused tail (1024 thr): lastcol -> rank-topk -> selective agg ->
// conv -> lin1 -> lin2. Ranking column gathered from compact hw127 (200 KB,
// L2-resident). Bitwise identical trees.
__global__ __launch_bounds__(1024) void tail_kernel(const float* __restrict__ hw,
                            const float* __restrict__ hw127,
                            const int* __restrict__ bstart, const int* __restrict__ row_ptr,
                            const int* __restrict__ csr_src, const float* __restrict__ dinv,
                            const float* __restrict__ b2,
                            const float* __restrict__ wT2, const float* __restrict__ conv_b,
                            const float* __restrict__ l1w, const float* __restrict__ l1b,
                            const float* __restrict__ l2w, const float* __restrict__ l2b,
                            float* __restrict__ out) {
    __shared__ float vals[CAP];          // 8 KB
    __shared__ float xcl[Kt][130];       // 15.6 KB, padded rows
    __shared__ float fl[CO * LOUT];      // 3.3 KB
    __shared__ float pz[8][Hd];          // 4 KB
    __shared__ float z[Hd];
    __shared__ int selS[Kt];
    int b = blockIdx.x, tid = threadIdx.x;

    int s0 = bstart[b], s1 = bstart[b + 1];
    int n = s1 - s0;
    int nc = n < CAP ? n : CAP;
    if (tid < Kt) selS[tid] = -1;
    // lastcol for own batch from compact hw127 (identical 8/4/1 tree)
    float b2l = b2[127];
    for (int j = tid; j < nc; j += 1024) {
        int node = s0 + j;
        float a0 = hw127[node];
        float a1 = 0.f, a2 = 0.f, a3 = 0.f, a4 = 0.f, a5 = 0.f, a6 = 0.f, a7 = 0.f;
        int e0 = row_ptr[node], e1 = row_ptr[node + 1];
        int e = e0;
        for (; e + 7 < e1; e += 8) {
            int q0 = __builtin_nontemporal_load(csr_src + e);
            int q1 = __builtin_nontemporal_load(csr_src + e + 1);
            int q2 = __builtin_nontemporal_load(csr_src + e + 2);
            int q3 = __builtin_nontemporal_load(csr_src + e + 3);
            int q4 = __builtin_nontemporal_load(csr_src + e + 4);
            int q5 = __builtin_nontemporal_load(csr_src + e + 5);
            int q6 = __builtin_nontemporal_load(csr_src + e + 6);
            int q7 = __builtin_nontemporal_load(csr_src + e + 7);
            a0 += hw127[q0];
            a1 += hw127[q1];
            a2 += hw127[q2];
            a3 += hw127[q3];
            a4 += hw127[q4];
            a5 += hw127[q5];
            a6 += hw127[q6];
            a7 += hw127[q7];
        }
        if (e + 3 < e1) {
            int q0 = __builtin_nontemporal_load(csr_src + e);
            int q1 = __builtin_nontemporal_load(csr_src + e + 1);
            int q2 = __builtin_nontemporal_load(csr_src + e + 2);
            int q3 = __builtin_nontemporal_load(csr_src + e + 3);
            a4 += hw127[q0];
            a5 += hw127[q1];
            a6 += hw127[q2];
            a7 += hw127[q3];
            e += 4;
        }
        for (; e < e1; ++e) {
            int q0 = __builtin_nontemporal_load(csr_src + e);
            a0 += hw127[q0];
        }
        float acc = ((a0 + a1) + (a2 + a3)) + ((a4 + a5) + (a6 + a7));
        vals[j] = fmaxf(fmaf(dinv[node], acc, b2l), 0.f);
    }
    __syncthreads();

    // rank pass (descending value, tie: smaller index)
    for (int j = tid; j < nc; j += 1024) {
        float vj = vals[j];
        int rank = 0;
        for (int i = 0; i < nc; ++i) {          // i wave-uniform -> LDS broadcast
            float vi = vals[i];
            rank += (vi > vj || (vi == vj && i < j)) ? 1 : 0;
        }
        if (rank < Kt) selS[rank] = s0 + j;
    }
    __syncthreads();

    // selective aggregation: one wave per selected node, identical tree to agg
    int wv = tid >> 6, lane = tid & 63;
    const v2f* hw2 = (const v2f*)hw;
    v2f bv = ((const v2f*)b2)[lane];
    for (int t = wv; t < Kt; t += 16) {
        int s = selS[t];
        v2f o = (v2f)0.f;
        if (s >= 0) {
            v2f a0 = hw2[(size_t)s * 64 + lane];
            v2f a1 = 0.f, a2 = 0.f, a3 = 0.f;
            v2f a4 = 0.f, a5 = 0.f, a6 = 0.f, a7 = 0.f;
            int e0 = row_ptr[s], e1 = row_ptr[s + 1];
            int e = e0;
            for (; e + 7 < e1; e += 8) {
                int q0 = __builtin_nontemporal_load(csr_src + e);
                int q1 = __builtin_nontemporal_load(csr_src + e + 1);
                int q2 = __builtin_nontemporal_load(csr_src + e + 2);
                int q3 = __builtin_nontemporal_load(csr_src + e + 3);
                int q4 = __builtin_nontemporal_load(csr_src + e + 4);
                int q5 = __builtin_nontemporal_load(csr_src + e + 5);
                int q6 = __builtin_nontemporal_load(csr_src + e + 6);
                int q7 = __builtin_nontemporal_load(csr_src + e + 7);
                a0 += hw2[(size_t)q0 * 64 + lane];
                a1 += hw2[(size_t)q1 * 64 + lane];
                a2 += hw2[(size_t)q2 * 64 + lane];
                a3 += hw2[(size_t)q3 * 64 + lane];
                a4 += hw2[(size_t)q4 * 64 + lane];
                a5 += hw2[(size_t)q5 * 64 + lane];
                a6 += hw2[(size_t)q6 * 64 + lane];
                a7 += hw2[(size_t)q7 * 64 + lane];
            }
            if (e + 3 < e1) {
                int q0 = __builtin_nontemporal_load(csr_src + e);
                int q1 = __builtin_nontemporal_load(csr_src + e + 1);
                int q2 = __builtin_nontemporal_load(csr_src + e + 2);
                int q3 = __builtin_nontemporal_load(csr_src + e + 3);
                a4 += hw2[(size_t)q0 * 64 + lane];
                a5 += hw2[(size_t)q1 * 64 + lane];
                a6 += hw2[(size_t)q2 * 64 + lane];
                a7 += hw2[(size_t)q3 * 64 + lane];
                e += 4;
            }
            for (; e < e1; ++e) {
                int q0 = __builtin_nontemporal_load(csr_src + e);
                a0 += hw2[(size_t)q0 * 64 + lane];
            }
            v2f acc = ((a0 + a1) + (a2 + a3)) + ((a4 + a5) + (a6 + a7));
            float d = dinv[s];
            o.x = fmaxf(fmaf(d, acc.x, bv.x), 0.f);
            o.y = fmaxf(fmaf(d, acc.y, bv.y), 0.f);
        }
        xcl[t][lane * 2] = o.x;
        xcl[t][lane * 2 + 1] = o.y;
    }
    __syncthreads();
    if (tid < CO * LOUT) {
        int o = tid / LOUT, t = tid - o * LOUT;
        float acc = conv_b[o];
#pragma unroll
        for (int k = 0; k < KW; ++k) {
            const float* xr = &xcl[t + k][0];
            const float* wr = wT2 + ((size_t)o * KW + k) * Hd;
#pragma unroll 8
            for (int c4 = 0; c4 < 32; ++c4) {
                float2 xa = *(const float2*)(xr + c4 * 4);
                float2 xb = *(const float2*)(xr + c4 * 4 + 2);
                float4 wv2 = *(const float4*)(wr + c4 * 4);
                acc = fmaf(xa.x, wv2.x, acc);
                acc = fmaf(xa.y, wv2.y, acc);
                acc = fmaf(xb.x, wv2.z, acc);
                acc = fmaf(xb.y, wv2.w, acc);
            }
        }
        fl[tid] = fmaxf(acc, 0.f);
    }
    __syncthreads();
    int hh = tid & 127, chunk = tid >> 7;
    int m0 = chunk * 104;
    float acc = 0.f;
    const float* lw = l1w + (size_t)m0 * Hd + hh;
#pragma unroll 8
    for (int m = 0; m < 104; ++m)
        acc = fmaf(fl[m0 + m], lw[(size_t)m * Hd], acc);
    pz[chunk][hh] = acc;
    __syncthreads();
    if (tid < Hd) {
        float a = l1b[tid];
#pragma unroll
        for (int q = 0; q < 8; ++q) a += pz[q][tid];
        z[tid] = fmaxf(a, 0.f);
    }
    __syncthreads();
    if (tid < 10) {
        float a2 = l2b[tid];
        for (int j = 0; j < Hd; ++j)
            a2 = fmaf(z[j], l2w[j * 10 + tid], a2);
        out[b * 10 + tid] = a2;
    }
}

extern "C" void kernel_launch(void* const* d_in, const int* in_sizes, int n_in,
                              void* d_out, int out_size, void* d_ws, size_t ws_size,
                              hipStream_t stream) {
    const float* x      = (const float*)d_in[0];
    const int*   ei     = (const int*)d_in[1];
    const int*   batch  = (const int*)d_in[2];
    const float* W0     = (const float*)d_in[3];
    const float* b0     = (const float*)d_in[4];
    const float* W1     = (const float*)d_in[5];
    const float* b1     = (const float*)d_in[6];
    const float* W2     = (const float*)d_in[7];
    const float* b2     = (const float*)d_in[8];
    const float* conv_w = (const float*)d_in[9];
    const float* conv_b = (const float*)d_in[10];
    const float* l1w    = (const float*)d_in[11];
    const float* l1b    = (const float*)d_in[12];
    const float* l2w    = (const float*)d_in[13];
    const float* l2b    = (const float*)d_in[14];
    float* out = (float*)d_out;

    // workspace layout — deg_i, cnt, bstart contiguous for one 0xFF memset
    int* wsI = (int*)d_ws;
    size_t off = 0;
    int*   deg_i   = wsI + off; off += Nn;
    int*   cnt     = wsI + off; off += Nn;
    int*   bstart  = wsI + off; off += 132;
    int*   row_ptr = wsI + off; off += 50004;
    float* dinv    = (float*)(wsI + off); off += Nn;
    int*   csr_src = wsI + off; off += Ee;
    off = (off + 3) & ~(size_t)3;        // 16B align
    ushort* Bph  = (ushort*)(wsI + off); off += 3 * 16384 / 2;   // packed W split hi
    ushort* Bpm  = (ushort*)(wsI + off); off += 3 * 16384 / 2;   // packed W split mid
    ushort* Bpl  = (ushort*)(wsI + off); off += 3 * 16384 / 2;   // packed W split lo
    float* hw    = (float*)(wsI + off); off += (size_t)Nn * Hd;
    float* hbuf  = (float*)(wsI + off); off += (size_t)Nn * Hd;
    float* wT2   = (float*)(wsI + off); off += CO * KW * Hd;
    float* hw127 = (float*)(wsI + off); off += Nn;

    // 1. set deg_i/cnt to -1, bstart to -1 sentinel (one DMA memset)
    hipMemsetAsync(deg_i, 0xFF, (size_t)(Nn + Nn + 132) * 4, stream);
    // 2. degree histogram + batch starts + W pack (one dispatch)
    countpack_kernel<<<(Ee + 255) / 256, 256, 0, stream>>>(ei, batch, deg_i, bstart,
        conv_w, wT2, W0, W1, W2, Bph, Bpm, Bpl);
    // 3. single-dispatch scan: direct offset sum + local scan + dinv + bstart fix
    scanBC2_kernel<<<SCB, 256, 0, stream>>>(deg_i, row_ptr, dinv, bstart);
    // 4. layer-0 matmul merged with CSR fill (independent work)
    mmxfill_kernel<<<MMB + (Ee + 255) / 256, 256, 0, stream>>>(x, Bph, Bpm, Bpl,
        dinv, hw, ei, row_ptr, cnt, csr_src);
    // 5. fused agg(b0)+matmul(W1) and agg(b1)+matmul(W2); 2nd emits hw127
    aggmm_kernel<<<MMB, 1024, 0, stream>>>(hw, row_ptr, csr_src, dinv, b0,
        Bph + 16384, Bpm + 16384, Bpl + 16384, hbuf, hw127);
    aggmm_kernel<<<MMB, 1024, 0, stream>>>(hbuf, row_ptr, csr_src, dinv, b1,
        Bph + 32768, Bpm + 32768, Bpl + 32768, hw, hw127);
    // 6. fused tail: lastcol(hw127) + rank-topk + selective agg + conv + lin1 + lin2
    tail_kernel<<<Bg, 1024, 0, stream>>>(hw, hw127, bstart, row_ptr, csr_src, dinv, b2,
                                         wT2, conv_b, l1w, l1b, l2w, l2b, out);
}

// Round 9
// 393.575 us; speedup vs baseline: 1.0026x; 1.0026x over previous
//
#include <hip/hip_runtime.h>
#include <math.h>

#define Nn 50000
#define Ee 600000
#define Bg 128      // batches (graphs)
#define Hd 128      // hidden dim
#define Kt 30       // sortpool K
#define CO 32       // conv out channels
#define KW 5        // conv kernel
#define LOUT 26     // K - KW + 1
#define CAP 2048    // per-batch node cap for topk LDS (max real count ~460)
#define SCB 196     // ceil(50000/256) scan blocks
#define MMB 782     // mmx blocks = ceil(50000/64)

typedef float v2f __attribute__((ext_vector_type(2)));
typedef short bf16x8 __attribute__((ext_vector_type(8)));
typedef float f32x4 __attribute__((ext_vector_type(4)));

// bf16 round-to-nearest-even helpers (branchless, finite inputs)
__device__ __forceinline__ unsigned short bfr(float v) {
    unsigned u = __builtin_bit_cast(unsigned, v);
    unsigned r = (u + 0x7FFFu + ((u >> 16) & 1u)) >> 16;
    return (unsigned short)r;
}
__device__ __forceinline__ float bff(unsigned short h) {
    unsigned u = ((unsigned)h) << 16;
    return __builtin_bit_cast(float, u);
}

// ---- count + batch starts + conv_w transpose + W 3-way split/pack ----------
// deg_i/cnt/bstart pre-set to -1 (0xFF memset). deg_i[c] ends at (#incoming - 1).
__global__ void countpack_kernel(const int* __restrict__ ei, const int* __restrict__ batch,
                            int* __restrict__ deg_i, int* __restrict__ bstart,
                            const float* __restrict__ conv_w, float* __restrict__ wT2,
                            const float* __restrict__ W0, const float* __restrict__ W1,
                            const float* __restrict__ W2,
                            ushort* __restrict__ Bph, ushort* __restrict__ Bpm,
                            ushort* __restrict__ Bpl) {
    int i = blockIdx.x * 256 + threadIdx.x;
    if (i < Ee) atomicAdd(&deg_i[ei[Ee + i]], 1);       // col = edge_index[1]
    if (i < Nn) {
        int b = batch[i];
        if (i == 0) bstart[b] = 0;
        else if (batch[i - 1] != b) bstart[b] = i;
    }
    if (i == 0) bstart[Bg] = Nn;
    if (i < CO * KW * Hd) {                     // wT2[o][k][ci] = conv_w[o][ci][k]
        int ci = i & 127;
        int r = i >> 7;          // o*KW + k
        int o = r / KW, k = r - o * KW;
        wT2[i] = conv_w[((size_t)o * Hd + ci) * KW + k];
    }
    if (i < 3 * 2048) {                          // W split+pack, B-fragment layout
        int l = i >> 11;
        int r = i & 2047;
        int kc = r >> 9;
        int n = (r >> 6) & 7;
        int lane = r & 63;
        int m = lane & 15, kq = lane >> 4;
        const float* W = (l == 0) ? W0 : (l == 1) ? W1 : W2;
        int col = n * 16 + m;
        size_t off = ((size_t)l * 2048 + (size_t)((kc * 8 + n) * 64 + lane)) * 8;
#pragma unroll
        for (int j = 0; j < 8; ++j) {
            float v = W[(size_t)(kc * 32 + kq * 8 + j) * Hd + col];
            unsigned short h = bfr(v);
            float r1 = v - bff(h);
            unsigned short mid = bfr(r1);
            Bph[off + j] = h;
            Bpm[off + j] = mid;
            Bpl[off + j] = bfr(r1 - bff(mid));
        }
    }
}

// ---- single scan dispatch: per-block direct offset sum + local scan + dinv --
__global__ __launch_bounds__(256) void scanBC2_kernel(const int* __restrict__ deg_i,
                            int* __restrict__ row_ptr, float* __restrict__ dinv,
                            int* __restrict__ bstart) {
    __shared__ int ls[256];
    __shared__ int boffS;
    int tid = threadIdx.x;
    int b = blockIdx.x;
    int s = 0;
    for (int k = 0; k < b; ++k)                 // j = k*256+tid < b*256 <= 49920 < Nn
        s += deg_i[k * 256 + tid] + 1;
    ls[tid] = s;
    __syncthreads();
    for (int off = 128; off > 0; off >>= 1) {
        if (tid < off) ls[tid] += ls[tid + off];
        __syncthreads();
    }
    if (tid == 0) boffS = ls[0];
    __syncthreads();
    int boff = boffS;
    int i = b * 256 + tid;
    int v2 = 0;
    if (i < Nn) {
        int raw = deg_i[i];
        v2 = raw + 1;                           // CSR row length (= #incoming)
        dinv[i] = 1.0f / sqrtf((float)(raw + 2));  // degree incl. self loop
    }
    ls[tid] = v2;
    __syncthreads();
    for (int off = 1; off < 256; off <<= 1) {
        int t = (tid >= off) ? ls[tid - off] : 0;
        __syncthreads();
        ls[tid] += t;
        __syncthreads();
    }
    if (i < Nn) row_ptr[i + 1] = ls[tid] + boff;
    if (i == 0) row_ptr[0] = 0;
    if (b == 0 && tid == 0) {   // empty batches inherit next start (batch sorted)
        for (int bb = Bg - 1; bb >= 0; --bb)
            if (bstart[bb] == -1) bstart[bb] = bstart[bb + 1];
    }
}

// ---------------- MFMA matmul body (shared by mmx and mmxfill) ----------------
// A-tile (contiguous 32KB) staged COALESCED into padded LDS [64][132]; fragment
// reads from LDS (2-way bank aliasing = free). Values bit-exact vs global path.
// 3-way split-bf16 (near-fp32). Retained products: a0b0,a1b0,a0b1,a1b1,a2b0,a0b2.
// Also emits column 127 (n=7,m=15) into compact col127[] (L2-resident ranking key).
__device__ __forceinline__ void mmx_body(int bid, int tid,
                            const float* __restrict__ Hin,
                            const ushort* __restrict__ Bph, const ushort* __restrict__ Bpm,
                            const ushort* __restrict__ Bpl,
                            const float* __restrict__ dinv, float* __restrict__ hw,
                            float* __restrict__ col127) {
    __shared__ __align__(16) float At[64][132];
    int w = tid >> 6, lane = tid & 63;
    int m = lane & 15, kq = lane >> 4;
    // ---- coalesced stage: rows bid*64.. (32 KB contiguous) -> LDS ----
    {
        const f32x4* g4 = (const f32x4*)(Hin + (size_t)bid * 64 * Hd);
        int rowsLeft = Nn - bid * 64;            // < 64 only for the last block
#pragma unroll
        for (int i = 0; i < 8; ++i) {
            int f = i * 256 + tid;               // float4 index in tile
            int r = f >> 5, c4 = f & 31;         // 32 float4 per row
            f32x4 v = (f32x4)0.f;
            if (r < rowsLeft) v = g4[f];
            *(f32x4*)&At[r][c4 * 4] = v;
        }
    }
    __syncthreads();
    const float* arow = &At[w * 16 + m][0];
    f32x4 acc[8];
#pragma unroll
    for (int n = 0; n < 8; ++n) acc[n] = (f32x4)0.f;
#pragma unroll
    for (int kc = 0; kc < 4; ++kc) {
        bf16x8 a0, a1, a2;
        float av[8];
        *(f32x4*)&av[0] = *(const f32x4*)(arow + kc * 32 + kq * 8);
        *(f32x4*)&av[4] = *(const f32x4*)(arow + kc * 32 + kq * 8 + 4);
#pragma unroll
        for (int j = 0; j < 8; ++j) {
            unsigned short h = bfr(av[j]);
            float r1 = av[j] - bff(h);
            unsigned short mid = bfr(r1);
            a0[j] = (short)h;
            a1[j] = (short)mid;
            a2[j] = (short)bfr(r1 - bff(mid));
        }
        const ushort* bhp = Bph + (size_t)((kc * 8) * 64 + lane) * 8;
        const ushort* bmp = Bpm + (size_t)((kc * 8) * 64 + lane) * 8;
        const ushort* blp = Bpl + (size_t)((kc * 8) * 64 + lane) * 8;
#pragma unroll
        for (int n = 0; n < 8; ++n) {
            bf16x8 b0 = *(const bf16x8*)(bhp + (size_t)n * 64 * 8);
            bf16x8 b1 = *(const bf16x8*)(bmp + (size_t)n * 64 * 8);
            bf16x8 b2 = *(const bf16x8*)(blp + (size_t)n * 64 * 8);
            acc[n] = __builtin_amdgcn_mfma_f32_16x16x32_bf16(a0, b0, acc[n], 0, 0, 0);
            acc[n] = __builtin_amdgcn_mfma_f32_16x16x32_bf16(a1, b0, acc[n], 0, 0, 0);
            acc[n] = __builtin_amdgcn_mfma_f32_16x16x32_bf16(a0, b1, acc[n], 0, 0, 0);
            acc[n] = __builtin_amdgcn_mfma_f32_16x16x32_bf16(a1, b1, acc[n], 0, 0, 0);
            acc[n] = __builtin_amdgcn_mfma_f32_16x16x32_bf16(a2, b0, acc[n], 0, 0, 0);
            acc[n] = __builtin_amdgcn_mfma_f32_16x16x32_bf16(a0, b2, acc[n], 0, 0, 0);
        }
    }
    int rbase = bid * 64 + w * 16 + kq * 4;
#pragma unroll
    for (int reg = 0; reg < 4; ++reg) {
        int r = rbase + reg;
        if (r < Nn) {
            float s = dinv[r];
#pragma unroll
            for (int n = 0; n < 8; ++n)
                hw[(size_t)r * Hd + n * 16 + m] = acc[n][reg] * s;
            if (m == 15) col127[r] = acc[7][reg] * s;   // same float as hw[r*128+127]
        }
    }
}

__global__ __launch_bounds__(256) void mmx_kernel(const float* __restrict__ Hin,
                            const ushort* __restrict__ Bph, const ushort* __restrict__ Bpm,
                            const ushort* __restrict__ Bpl,
                            const float* __restrict__ dinv, float* __restrict__ hw,
                            float* __restrict__ col127) {
    mmx_body(blockIdx.x, threadIdx.x, Hin, Bph, Bpm, Bpl, dinv, hw, col127);
}

// ---- merged layer-0 matmul + CSR fill (independent work, block-range split) --
__global__ __launch_bounds__(256) void mmxfill_kernel(const float* __restrict__ Hin,
                            const ushort* __restrict__ Bph, const ushort* __restrict__ Bpm,
                            const ushort* __restrict__ Bpl,
                            const float* __restrict__ dinv, float* __restrict__ hw,
                            float* __restrict__ col127,
                            const int* __restrict__ ei, const int* __restrict__ row_ptr,
                            int* __restrict__ cnt, int* __restrict__ csr_src) {
    if (blockIdx.x < MMB) {
        mmx_body(blockIdx.x, threadIdx.x, Hin, Bph, Bpm, Bpl, dinv, hw, col127);
    } else {
        int e = (blockIdx.x - MMB) * 256 + threadIdx.x;
        if (e < Ee) {
            int c = ei[Ee + e];
            int r = ei[e];
            int p = row_ptr[c] + atomicAdd(&cnt[c], 1) + 1;   // cnt starts at -1
            csr_src[p] = r;
        }
    }
}

// ---------------- aggregation: h[i] = relu(dinv[i]*(hw[i] + sum_src hw[src]) + b) ----
// 8-way unrolled gather (8 outstanding 512B row-loads per wave) + 4/1 remainder.
__global__ __launch_bounds__(256) void agg_kernel(const float* __restrict__ hw,
                            const int* __restrict__ row_ptr, const int* __restrict__ csr_src,
                            const float* __restrict__ dinv, const float* __restrict__ bias,
                            float* __restrict__ hout) {
    int node = blockIdx.x * 4 + (threadIdx.x >> 6);
    if (node >= Nn) return;
    int lane = threadIdx.x & 63;
    const v2f* hw2 = (const v2f*)hw;
    v2f a0 = hw2[(size_t)node * 64 + lane];   // self loop (hw pre-scaled by dinv[src])
    v2f a1 = 0.f, a2 = 0.f, a3 = 0.f;
    v2f a4 = 0.f, a5 = 0.f, a6 = 0.f, a7 = 0.f;
    int e0 = row_ptr[node], e1 = row_ptr[node + 1];
    int e = e0;
    for (; e + 7 < e1; e += 8) {
        int s0 = __builtin_nontemporal_load(csr_src + e);
        int s1 = __builtin_nontemporal_load(csr_src + e + 1);
        int s2 = __builtin_nontemporal_load(csr_src + e + 2);
        int s3 = __builtin_nontemporal_load(csr_src + e + 3);
        int s4 = __builtin_nontemporal_load(csr_src + e + 4);
        int s5 = __builtin_nontemporal_load(csr_src + e + 5);
        int s6 = __builtin_nontemporal_load(csr_src + e + 6);
        int s7 = __builtin_nontemporal_load(csr_src + e + 7);
        a0 += hw2[(size_t)s0 * 64 + lane];
        a1 += hw2[(size_t)s1 * 64 + lane];
        a2 += hw2[(size_t)s2 * 64 + lane];
        a3 += hw2[(size_t)s3 * 64 + lane];
        a4 += hw2[(size_t)s4 * 64 + lane];
        a5 += hw2[(size_t)s5 * 64 + lane];
        a6 += hw2[(size_t)s6 * 64 + lane];
        a7 += hw2[(size_t)s7 * 64 + lane];
    }
    if (e + 3 < e1) {
        int s0 = __builtin_nontemporal_load(csr_src + e);
        int s1 = __builtin_nontemporal_load(csr_src + e + 1);
        int s2 = __builtin_nontemporal_load(csr_src + e + 2);
        int s3 = __builtin_nontemporal_load(csr_src + e + 3);
        a4 += hw2[(size_t)s0 * 64 + lane];
        a5 += hw2[(size_t)s1 * 64 + lane];
        a6 += hw2[(size_t)s2 * 64 + lane];
        a7 += hw2[(size_t)s3 * 64 + lane];
        e += 4;
    }
    for (; e < e1; ++e) {
        int s0 = __builtin_nontemporal_load(csr_src + e);
        a0 += hw2[(size_t)s0 * 64 + lane];
    }
    v2f acc = ((a0 + a1) + (a2 + a3)) + ((a4 + a5) + (a6 + a7));
    float d = dinv[node];
    v2f bv = ((const v2f*)bias)[lane];
    v2f o;
    o.x = fmaxf(fmaf(d, acc.x, bv.x), 0.f);
    o.y = fmaxf(fmaf(d, acc.y, bv.y), 0.f);
    ((v2f*)hout)[(size_t)node * 64 + lane] = o;
}

// ---------------- fused tail (1024 thr): lastcol -> rank-topk -> selective agg ->
// conv -> lin1 -> lin2. Ranking column gathered from compact hw127 (200 KB,
// L2-resident) instead of strided hw column (64B line per 4B). Bitwise identical.
__global__ __launch_bounds__(1024) void tail_kernel(const float* __restrict__ hw,
                            const float* __restrict__ hw127,
                            const int* __restrict__ bstart, const int* __restrict__ row_ptr,
                            const int* __restrict__ csr_src, const float* __restrict__ dinv,
                            const float* __restrict__ b2,
                            const float* __restrict__ wT2, const float* __restrict__ conv_b,
                            const float* __restrict__ l1w, const float* __restrict__ l1b,
                            const float* __restrict__ l2w, const float* __restrict__ l2b,
                            float* __restrict__ out) {
    __shared__ float vals[CAP];          // 8 KB
    __shared__ float xcl[Kt][130];       // 15.6 KB, padded rows
    __shared__ float fl[CO * LOUT];      // 3.3 KB
    __shared__ float pz[8][Hd];          // 4 KB
    __shared__ float z[Hd];
    __shared__ int selS[Kt];
    int b = blockIdx.x, tid = threadIdx.x;

    int s0 = bstart[b], s1 = bstart[b + 1];
    int n = s1 - s0;
    int nc = n < CAP ? n : CAP;
    if (tid < Kt) selS[tid] = -1;
    // lastcol for own batch from compact hw127 (identical 8/4/1 tree)
    float b2l = b2[127];
    for (int j = tid; j < nc; j += 1024) {
        int node = s0 + j;
        float a0 = hw127[node];
        float a1 = 0.f, a2 = 0.f, a3 = 0.f, a4 = 0.f, a5 = 0.f, a6 = 0.f, a7 = 0.f;
        int e0 = row_ptr[node], e1 = row_ptr[node + 1];
        int e = e0;
        for (; e + 7 < e1; e += 8) {
            int q0 = __builtin_nontemporal_load(csr_src + e);
            int q1 = __builtin_nontemporal_load(csr_src + e + 1);
            int q2 = __builtin_nontemporal_load(csr_src + e + 2);
            int q3 = __builtin_nontemporal_load(csr_src + e + 3);
            int q4 = __builtin_nontemporal_load(csr_src + e + 4);
            int q5 = __builtin_nontemporal_load(csr_src + e + 5);
            int q6 = __builtin_nontemporal_load(csr_src + e + 6);
            int q7 = __builtin_nontemporal_load(csr_src + e + 7);
            a0 += hw127[q0];
            a1 += hw127[q1];
            a2 += hw127[q2];
            a3 += hw127[q3];
            a4 += hw127[q4];
            a5 += hw127[q5];
            a6 += hw127[q6];
            a7 += hw127[q7];
        }
        if (e + 3 < e1) {
            int q0 = __builtin_nontemporal_load(csr_src + e);
            int q1 = __builtin_nontemporal_load(csr_src + e + 1);
            int q2 = __builtin_nontemporal_load(csr_src + e + 2);
            int q3 = __builtin_nontemporal_load(csr_src + e + 3);
            a4 += hw127[q0];
            a5 += hw127[q1];
            a6 += hw127[q2];
            a7 += hw127[q3];
            e += 4;
        }
        for (; e < e1; ++e) {
            int q0 = __builtin_nontemporal_load(csr_src + e);
            a0 += hw127[q0];
        }
        float acc = ((a0 + a1) + (a2 + a3)) + ((a4 + a5) + (a6 + a7));
        vals[j] = fmaxf(fmaf(dinv[node], acc, b2l), 0.f);
    }
    __syncthreads();

    // rank pass (descending value, tie: smaller index)
    for (int j = tid; j < nc; j += 1024) {
        float vj = vals[j];
        int rank = 0;
        for (int i = 0; i < nc; ++i) {          // i wave-uniform -> LDS broadcast
            float vi = vals[i];
            rank += (vi > vj || (vi == vj && i < j)) ? 1 : 0;
        }
        if (rank < Kt) selS[rank] = s0 + j;
    }
    __syncthreads();

    // selective aggregation: one wave per selected node, identical tree to agg
    int wv = tid >> 6, lane = tid & 63;
    const v2f* hw2 = (const v2f*)hw;
    v2f bv = ((const v2f*)b2)[lane];
    for (int t = wv; t < Kt; t += 16) {
        int s = selS[t];
        v2f o = (v2f)0.f;
        if (s >= 0) {
            v2f a0 = hw2[(size_t)s * 64 + lane];
            v2f a1 = 0.f, a2 = 0.f, a3 = 0.f;
            v2f a4 = 0.f, a5 = 0.f, a6 = 0.f, a7 = 0.f;
            int e0 = row_ptr[s], e1 = row_ptr[s + 1];
            int e = e0;
            for (; e + 7 < e1; e += 8) {
                int q0 = __builtin_nontemporal_load(csr_src + e);
                int q1 = __builtin_nontemporal_load(csr_src + e + 1);
                int q2 = __builtin_nontemporal_load(csr_src + e + 2);
                int q3 = __builtin_nontemporal_load(csr_src + e + 3);
                int q4 = __builtin_nontemporal_load(csr_src + e + 4);
                int q5 = __builtin_nontemporal_load(csr_src + e + 5);
                int q6 = __builtin_nontemporal_load(csr_src + e + 6);
                int q7 = __builtin_nontemporal_load(csr_src + e + 7);
                a0 += hw2[(size_t)q0 * 64 + lane];
                a1 += hw2[(size_t)q1 * 64 + lane];
                a2 += hw2[(size_t)q2 * 64 + lane];
                a3 += hw2[(size_t)q3 * 64 + lane];
                a4 += hw2[(size_t)q4 * 64 + lane];
                a5 += hw2[(size_t)q5 * 64 + lane];
                a6 += hw2[(size_t)q6 * 64 + lane];
                a7 += hw2[(size_t)q7 * 64 + lane];
            }
            if (e + 3 < e1) {
                int q0 = __builtin_nontemporal_load(csr_src + e);
                int q1 = __builtin_nontemporal_load(csr_src + e + 1);
                int q2 = __builtin_nontemporal_load(csr_src + e + 2);
                int q3 = __builtin_nontemporal_load(csr_src + e + 3);
                a4 += hw2[(size_t)q0 * 64 + lane];
                a5 += hw2[(size_t)q1 * 64 + lane];
                a6 += hw2[(size_t)q2 * 64 + lane];
                a7 += hw2[(size_t)q3 * 64 + lane];
                e += 4;
            }
            for (; e < e1; ++e) {
                int q0 = __builtin_nontemporal_load(csr_src + e);
                a0 += hw2[(size_t)q0 * 64 + lane];
            }
            v2f acc = ((a0 + a1) + (a2 + a3)) + ((a4 + a5) + (a6 + a7));
            float d = dinv[s];
            o.x = fmaxf(fmaf(d, acc.x, bv.x), 0.f);
            o.y = fmaxf(fmaf(d, acc.y, bv.y), 0.f);
        }
        xcl[t][lane * 2] = o.x;
        xcl[t][lane * 2 + 1] = o.y;
    }
    __syncthreads();
    if (tid < CO * LOUT) {
        int o = tid / LOUT, t = tid - o * LOUT;
        float acc = conv_b[o];
#pragma unroll
        for (int k = 0; k < KW; ++k) {
            const float* xr = &xcl[t + k][0];
            const float* wr = wT2 + ((size_t)o * KW + k) * Hd;
#pragma unroll 8
            for (int c4 = 0; c4 < 32; ++c4) {
                float2 xa = *(const float2*)(xr + c4 * 4);
                float2 xb = *(const float2*)(xr + c4 * 4 + 2);
                float4 wv2 = *(const float4*)(wr + c4 * 4);
                acc = fmaf(xa.x, wv2.x, acc);
                acc = fmaf(xa.y, wv2.y, acc);
                acc = fmaf(xb.x, wv2.z, acc);
                acc = fmaf(xb.y, wv2.w, acc);
            }
        }
        fl[tid] = fmaxf(acc, 0.f);
    }
    __syncthreads();
    int hh = tid & 127, chunk = tid >> 7;
    int m0 = chunk * 104;
    float acc = 0.f;
    const float* lw = l1w + (size_t)m0 * Hd + hh;
#pragma unroll 8
    for (int m = 0; m < 104; ++m)
        acc = fmaf(fl[m0 + m], lw[(size_t)m * Hd], acc);
    pz[chunk][hh] = acc;
    __syncthreads();
    if (tid < Hd) {
        float a = l1b[tid];
#pragma unroll
        for (int q = 0; q < 8; ++q) a += pz[q][tid];
        z[tid] = fmaxf(a, 0.f);
    }
    __syncthreads();
    if (tid < 10) {
        float a2 = l2b[tid];
        for (int j = 0; j < Hd; ++j)
            a2 = fmaf(z[j], l2w[j * 10 + tid], a2);
        out[b * 10 + tid] = a2;
    }
}

extern "C" void kernel_launch(void* const* d_in, const int* in_sizes, int n_in,
                              void* d_out, int out_size, void* d_ws, size_t ws_size,
                              hipStream_t stream) {
    const float* x      = (const float*)d_in[0];
    const int*   ei     = (const int*)d_in[1];
    const int*   batch  = (const int*)d_in[2];
    const float* W0     = (const float*)d_in[3];
    const float* b0     = (const float*)d_in[4];
    const float* W1     = (const float*)d_in[5];
    const float* b1     = (const float*)d_in[6];
    const float* W2     = (const float*)d_in[7];
    const float* b2     = (const float*)d_in[8];
    const float* conv_w = (const float*)d_in[9];
    const float* conv_b = (const float*)d_in[10];
    const float* l1w    = (const float*)d_in[11];
    const float* l1b    = (const float*)d_in[12];
    const float* l2w    = (const float*)d_in[13];
    const float* l2b    = (const float*)d_in[14];
    float* out = (float*)d_out;

    // workspace layout — deg_i, cnt, bstart contiguous for one 0xFF memset
    int* wsI = (int*)d_ws;
    size_t off = 0;
    int*   deg_i   = wsI + off; off += Nn;
    int*   cnt     = wsI + off; off += Nn;
    int*   bstart  = wsI + off; off += 132;
    int*   row_ptr = wsI + off; off += 50004;
    float* dinv    = (float*)(wsI + off); off += Nn;
    int*   csr_src = wsI + off; off += Ee;
    off = (off + 3) & ~(size_t)3;        // 16B align
    ushort* Bph  = (ushort*)(wsI + off); off += 3 * 16384 / 2;   // packed W split hi
    ushort* Bpm  = (ushort*)(wsI + off); off += 3 * 16384 / 2;   // packed W split mid
    ushort* Bpl  = (ushort*)(wsI + off); off += 3 * 16384 / 2;   // packed W split lo
    float* hw    = (float*)(wsI + off); off += (size_t)Nn * Hd;
    float* hbuf  = (float*)(wsI + off); off += (size_t)Nn * Hd;
    float* wT2   = (float*)(wsI + off); off += CO * KW * Hd;
    float* hw127 = (float*)(wsI + off); off += Nn;

    // 1. set deg_i/cnt to -1, bstart to -1 sentinel (one DMA memset)
    hipMemsetAsync(deg_i, 0xFF, (size_t)(Nn + Nn + 132) * 4, stream);
    // 2. degree histogram + batch starts + W pack (one dispatch)
    countpack_kernel<<<(Ee + 255) / 256, 256, 0, stream>>>(ei, batch, deg_i, bstart,
        conv_w, wT2, W0, W1, W2, Bph, Bpm, Bpl);
    // 3. single-dispatch scan: direct offset sum + local scan + dinv + bstart fix
    scanBC2_kernel<<<SCB, 256, 0, stream>>>(deg_i, row_ptr, dinv, bstart);
    // 4. layer-0 matmul merged with CSR fill (independent work)
    dim3 aggGrid((Nn + 3) / 4);
    mmxfill_kernel<<<MMB + (Ee + 255) / 256, 256, 0, stream>>>(x, Bph, Bpm, Bpl,
        dinv, hw, hw127, ei, row_ptr, cnt, csr_src);
    agg_kernel<<<aggGrid, 256, 0, stream>>>(hw, row_ptr, csr_src, dinv, b0, hbuf);
    // 5. layers 1,2 (layer-2 matmul also emits compact ranking column hw127)
    mmx_kernel<<<MMB, 256, 0, stream>>>(hbuf, Bph + 16384, Bpm + 16384, Bpl + 16384,
        dinv, hw, hw127);
    agg_kernel<<<aggGrid, 256, 0, stream>>>(hw, row_ptr, csr_src, dinv, b1, hbuf);
    mmx_kernel<<<MMB, 256, 0, stream>>>(hbuf, Bph + 32768, Bpm + 32768, Bpl + 32768,
        dinv, hw, hw127);
    // 6. fused tail: lastcol(hw127) + rank-topk + selective agg + conv + lin1 + lin2
    tail_kernel<<<Bg, 1024, 0, stream>>>(hw, hw127, bstart, row_ptr, csr_src, dinv, b2,
                                         wT2, conv_b, l1w, l1b, l2w, l2b, out);
}

// Round 10
// 388.783 us; speedup vs baseline: 1.0150x; 1.0123x over previous
//
#include <hip/hip_runtime.h>
#include <math.h>

#define Nn 50000
#define Ee 600000
#define Bg 128      // batches (graphs)
#define Hd 128      // hidden dim
#define Kt 30       // sortpool K
#define CO 32       // conv out channels
#define KW 5        // conv kernel
#define LOUT 26     // K - KW + 1
#define CAP 2048    // per-batch node cap for topk LDS (max real count ~460)
#define SCB 196     // ceil(50000/256) scan blocks
#define MMB 782     // mmx blocks = ceil(50000/64)

typedef float v2f __attribute__((ext_vector_type(2)));
typedef short bf16x8 __attribute__((ext_vector_type(8)));
typedef float f32x4 __attribute__((ext_vector_type(4)));

// bf16 round-to-nearest-even helpers (branchless, finite inputs)
__device__ __forceinline__ unsigned short bfr(float v) {
    unsigned u = __builtin_bit_cast(unsigned, v);
    unsigned r = (u + 0x7FFFu + ((u >> 16) & 1u)) >> 16;
    return (unsigned short)r;
}
__device__ __forceinline__ float bff(unsigned short h) {
    unsigned u = ((unsigned)h) << 16;
    return __builtin_bit_cast(float, u);
}

// ---- count + batch starts + conv_w transpose + W 3-way split/pack ----------
// deg_i/cnt/bstart pre-set to -1 (0xFF memset). deg_i[c] ends at (#incoming - 1).
__global__ void countpack_kernel(const int* __restrict__ ei, const int* __restrict__ batch,
                            int* __restrict__ deg_i, int* __restrict__ bstart,
                            const float* __restrict__ conv_w, float* __restrict__ wT2,
                            const float* __restrict__ W0, const float* __restrict__ W1,
                            const float* __restrict__ W2,
                            ushort* __restrict__ Bph, ushort* __restrict__ Bpm,
                            ushort* __restrict__ Bpl) {
    int i = blockIdx.x * 256 + threadIdx.x;
    if (i < Ee) atomicAdd(&deg_i[ei[Ee + i]], 1);       // col = edge_index[1]
    if (i < Nn) {
        int b = batch[i];
        if (i == 0) bstart[b] = 0;
        else if (batch[i - 1] != b) bstart[b] = i;
    }
    if (i == 0) bstart[Bg] = Nn;
    if (i < CO * KW * Hd) {                     // wT2[o][k][ci] = conv_w[o][ci][k]
        int ci = i & 127;
        int r = i >> 7;          // o*KW + k
        int o = r / KW, k = r - o * KW;
        wT2[i] = conv_w[((size_t)o * Hd + ci) * KW + k];
    }
    if (i < 3 * 2048) {                          // W split+pack, B-fragment layout
        int l = i >> 11;
        int r = i & 2047;
        int kc = r >> 9;
        int n = (r >> 6) & 7;
        int lane = r & 63;
        int m = lane & 15, kq = lane >> 4;
        const float* W = (l == 0) ? W0 : (l == 1) ? W1 : W2;
        int col = n * 16 + m;
        size_t off = ((size_t)l * 2048 + (size_t)((kc * 8 + n) * 64 + lane)) * 8;
#pragma unroll
        for (int j = 0; j < 8; ++j) {
            float v = W[(size_t)(kc * 32 + kq * 8 + j) * Hd + col];
            unsigned short h = bfr(v);
            float r1 = v - bff(h);
            unsigned short mid = bfr(r1);
            Bph[off + j] = h;
            Bpm[off + j] = mid;
            Bpl[off + j] = bfr(r1 - bff(mid));
        }
    }
}

// ---- single scan dispatch: per-block direct offset sum + local scan + dinv --
__global__ __launch_bounds__(256) void scanBC2_kernel(const int* __restrict__ deg_i,
                            int* __restrict__ row_ptr, float* __restrict__ dinv,
                            int* __restrict__ bstart) {
    __shared__ int ls[256];
    __shared__ int boffS;
    int tid = threadIdx.x;
    int b = blockIdx.x;
    int s = 0;
    for (int k = 0; k < b; ++k)                 // j = k*256+tid < b*256 <= 49920 < Nn
        s += deg_i[k * 256 + tid] + 1;
    ls[tid] = s;
    __syncthreads();
    for (int off = 128; off > 0; off >>= 1) {
        if (tid < off) ls[tid] += ls[tid + off];
        __syncthreads();
    }
    if (tid == 0) boffS = ls[0];
    __syncthreads();
    int boff = boffS;
    int i = b * 256 + tid;
    int v2 = 0;
    if (i < Nn) {
        int raw = deg_i[i];
        v2 = raw + 1;                           // CSR row length (= #incoming)
        dinv[i] = 1.0f / sqrtf((float)(raw + 2));  // degree incl. self loop
    }
    ls[tid] = v2;
    __syncthreads();
    for (int off = 1; off < 256; off <<= 1) {
        int t = (tid >= off) ? ls[tid - off] : 0;
        __syncthreads();
        ls[tid] += t;
        __syncthreads();
    }
    if (i < Nn) row_ptr[i + 1] = ls[tid] + boff;
    if (i == 0) row_ptr[0] = 0;
    if (b == 0 && tid == 0) {   // empty batches inherit next start (batch sorted)
        for (int bb = Bg - 1; bb >= 0; --bb)
            if (bstart[bb] == -1) bstart[bb] = bstart[bb + 1];
    }
}

// ---------------- MFMA matmul body (shared by mmx and mmxfill) ----------------
// A-tile (contiguous 32KB) staged COALESCED into padded LDS [64][132]; fragment
// reads from LDS. 3-way split-bf16 (near-fp32). EPILOGUE: accumulator routed
// back through the wave's own At stripe (wave-private rows, in-order DS pipe,
// no barrier) and stored with 8 coalesced f32x4 per lane (2 rows/1024B per
// instruction) instead of 32 scalar 4B scatter stores. Bit-exact values.
// Also emits column 127 into compact col127[] (L2-resident ranking key).
__device__ __forceinline__ void mmx_body(int bid, int tid,
                            const float* __restrict__ Hin,
                            const ushort* __restrict__ Bph, const ushort* __restrict__ Bpm,
                            const ushort* __restrict__ Bpl,
                            const float* __restrict__ dinv, float* __restrict__ hw,
                            float* __restrict__ col127) {
    __shared__ __align__(16) float At[64][132];
    int w = tid >> 6, lane = tid & 63;
    int m = lane & 15, kq = lane >> 4;
    // ---- coalesced stage: rows bid*64.. (32 KB contiguous) -> LDS ----
    {
        const f32x4* g4 = (const f32x4*)(Hin + (size_t)bid * 64 * Hd);
        int rowsLeft = Nn - bid * 64;            // < 64 only for the last block
#pragma unroll
        for (int i = 0; i < 8; ++i) {
            int f = i * 256 + tid;               // float4 index in tile
            int r = f >> 5, c4 = f & 31;         // 32 float4 per row
            f32x4 v = (f32x4)0.f;
            if (r < rowsLeft) v = g4[f];
            *(f32x4*)&At[r][c4 * 4] = v;
        }
    }
    __syncthreads();
    const float* arow = &At[w * 16 + m][0];
    f32x4 acc[8];
#pragma unroll
    for (int n = 0; n < 8; ++n) acc[n] = (f32x4)0.f;
#pragma unroll
    for (int kc = 0; kc < 4; ++kc) {
        bf16x8 a0, a1, a2;
        float av[8];
        *(f32x4*)&av[0] = *(const f32x4*)(arow + kc * 32 + kq * 8);
        *(f32x4*)&av[4] = *(const f32x4*)(arow + kc * 32 + kq * 8 + 4);
#pragma unroll
        for (int j = 0; j < 8; ++j) {
            unsigned short h = bfr(av[j]);
            float r1 = av[j] - bff(h);
            unsigned short mid = bfr(r1);
            a0[j] = (short)h;
            a1[j] = (short)mid;
            a2[j] = (short)bfr(r1 - bff(mid));
        }
        const ushort* bhp = Bph + (size_t)((kc * 8) * 64 + lane) * 8;
        const ushort* bmp = Bpm + (size_t)((kc * 8) * 64 + lane) * 8;
        const ushort* blp = Bpl + (size_t)((kc * 8) * 64 + lane) * 8;
#pragma unroll
        for (int n = 0; n < 8; ++n) {
            bf16x8 b0 = *(const bf16x8*)(bhp + (size_t)n * 64 * 8);
            bf16x8 b1 = *(const bf16x8*)(bmp + (size_t)n * 64 * 8);
            bf16x8 b2 = *(const bf16x8*)(blp + (size_t)n * 64 * 8);
            acc[n] = __builtin_amdgcn_mfma_f32_16x16x32_bf16(a0, b0, acc[n], 0, 0, 0);
            acc[n] = __builtin_amdgcn_mfma_f32_16x16x32_bf16(a1, b0, acc[n], 0, 0, 0);
            acc[n] = __builtin_amdgcn_mfma_f32_16x16x32_bf16(a0, b1, acc[n], 0, 0, 0);
            acc[n] = __builtin_amdgcn_mfma_f32_16x16x32_bf16(a1, b1, acc[n], 0, 0, 0);
            acc[n] = __builtin_amdgcn_mfma_f32_16x16x32_bf16(a2, b0, acc[n], 0, 0, 0);
            acc[n] = __builtin_amdgcn_mfma_f32_16x16x32_bf16(a0, b2, acc[n], 0, 0, 0);
        }
    }
    // ---- epilogue: acc -> own At stripe (wave-private, no barrier) ----
#pragma unroll
    for (int reg = 0; reg < 4; ++reg) {
        int rl = kq * 4 + reg;                  // local row in stripe
        int r = bid * 64 + w * 16 + rl;
        float sc = (r < Nn) ? dinv[r] : 0.f;
#pragma unroll
        for (int n = 0; n < 8; ++n)
            At[w * 16 + rl][n * 16 + m] = acc[n][reg] * sc;
        if (m == 15 && r < Nn) col127[r] = acc[7][reg] * sc;  // = hw[r*128+127]
    }
    // ---- coalesced vector store: 2 rows (1024B) per instruction, 8 iters ----
    int half = lane >> 5;                       // 0/1: which of the 2 rows
    int cc = (lane & 31) * 4;                   // column (float index)
#pragma unroll
    for (int i = 0; i < 8; ++i) {
        int rl = i * 2 + half;
        int r = bid * 64 + w * 16 + rl;
        f32x4 v = *(const f32x4*)&At[w * 16 + rl][cc];
        if (r < Nn)
            *(f32x4*)&hw[(size_t)r * Hd + cc] = v;
    }
}

__global__ __launch_bounds__(256) void mmx_kernel(const float* __restrict__ Hin,
                            const ushort* __restrict__ Bph, const ushort* __restrict__ Bpm,
                            const ushort* __restrict__ Bpl,
                            const float* __restrict__ dinv, float* __restrict__ hw,
                            float* __restrict__ col127) {
    mmx_body(blockIdx.x, threadIdx.x, Hin, Bph, Bpm, Bpl, dinv, hw, col127);
}

// ---- merged layer-0 matmul + CSR fill (independent work, block-range split) --
__global__ __launch_bounds__(256) void mmxfill_kernel(const float* __restrict__ Hin,
                            const ushort* __restrict__ Bph, const ushort* __restrict__ Bpm,
                            const ushort* __restrict__ Bpl,
                            const float* __restrict__ dinv, float* __restrict__ hw,
                            float* __restrict__ col127,
                            const int* __restrict__ ei, const int* __restrict__ row_ptr,
                            int* __restrict__ cnt, int* __restrict__ csr_src) {
    if (blockIdx.x < MMB) {
        mmx_body(blockIdx.x, threadIdx.x, Hin, Bph, Bpm, Bpl, dinv, hw, col127);
    } else {
        int e = (blockIdx.x - MMB) * 256 + threadIdx.x;
        if (e < Ee) {
            int c = ei[Ee + e];
            int r = ei[e];
            int p = row_ptr[c] + atomicAdd(&cnt[c], 1) + 1;   // cnt starts at -1
            csr_src[p] = r;
        }
    }
}

// ---------------- aggregation: h[i] = relu(dinv[i]*(hw[i] + sum_src hw[src]) + b) ----
// 8-way unrolled gather (8 outstanding 512B row-loads per wave) + 4/1 remainder.
__global__ __launch_bounds__(256) void agg_kernel(const float* __restrict__ hw,
                            const int* __restrict__ row_ptr, const int* __restrict__ csr_src,
                            const float* __restrict__ dinv, const float* __restrict__ bias,
                            float* __restrict__ hout) {
    int node = blockIdx.x * 4 + (threadIdx.x >> 6);
    if (node >= Nn) return;
    int lane = threadIdx.x & 63;
    const v2f* hw2 = (const v2f*)hw;
    v2f a0 = hw2[(size_t)node * 64 + lane];   // self loop (hw pre-scaled by dinv[src])
    v2f a1 = 0.f, a2 = 0.f, a3 = 0.f;
    v2f a4 = 0.f, a5 = 0.f, a6 = 0.f, a7 = 0.f;
    int e0 = row_ptr[node], e1 = row_ptr[node + 1];
    int e = e0;
    for (; e + 7 < e1; e += 8) {
        int s0 = __builtin_nontemporal_load(csr_src + e);
        int s1 = __builtin_nontemporal_load(csr_src + e + 1);
        int s2 = __builtin_nontemporal_load(csr_src + e + 2);
        int s3 = __builtin_nontemporal_load(csr_src + e + 3);
        int s4 = __builtin_nontemporal_load(csr_src + e + 4);
        int s5 = __builtin_nontemporal_load(csr_src + e + 5);
        int s6 = __builtin_nontemporal_load(csr_src + e + 6);
        int s7 = __builtin_nontemporal_load(csr_src + e + 7);
        a0 += hw2[(size_t)s0 * 64 + lane];
        a1 += hw2[(size_t)s1 * 64 + lane];
        a2 += hw2[(size_t)s2 * 64 + lane];
        a3 += hw2[(size_t)s3 * 64 + lane];
        a4 += hw2[(size_t)s4 * 64 + lane];
        a5 += hw2[(size_t)s5 * 64 + lane];
        a6 += hw2[(size_t)s6 * 64 + lane];
        a7 += hw2[(size_t)s7 * 64 + lane];
    }
    if (e + 3 < e1) {
        int s0 = __builtin_nontemporal_load(csr_src + e);
        int s1 = __builtin_nontemporal_load(csr_src + e + 1);
        int s2 = __builtin_nontemporal_load(csr_src + e + 2);
        int s3 = __builtin_nontemporal_load(csr_src + e + 3);
        a4 += hw2[(size_t)s0 * 64 + lane];
        a5 += hw2[(size_t)s1 * 64 + lane];
        a6 += hw2[(size_t)s2 * 64 + lane];
        a7 += hw2[(size_t)s3 * 64 + lane];
        e += 4;
    }
    for (; e < e1; ++e) {
        int s0 = __builtin_nontemporal_load(csr_src + e);
        a0 += hw2[(size_t)s0 * 64 + lane];
    }
    v2f acc = ((a0 + a1) + (a2 + a3)) + ((a4 + a5) + (a6 + a7));
    float d = dinv[node];
    v2f bv = ((const v2f*)bias)[lane];
    v2f o;
    o.x = fmaxf(fmaf(d, acc.x, bv.x), 0.f);
    o.y = fmaxf(fmaf(d, acc.y, bv.y), 0.f);
    ((v2f*)hout)[(size_t)node * 64 + lane] = o;
}

// ---------------- fused tail (1024 thr): lastcol -> rank-topk -> selective agg ->
// conv -> lin1 -> lin2. Ranking column gathered from compact hw127 (200 KB,
// L2-resident). Bitwise identical trees.
__global__ __launch_bounds__(1024) void tail_kernel(const float* __restrict__ hw,
                            const float* __restrict__ hw127,
                            const int* __restrict__ bstart, const int* __restrict__ row_ptr,
                            const int* __restrict__ csr_src, const float* __restrict__ dinv,
                            const float* __restrict__ b2,
                            const float* __restrict__ wT2, const float* __restrict__ conv_b,
                            const float* __restrict__ l1w, const float* __restrict__ l1b,
                            const float* __restrict__ l2w, const float* __restrict__ l2b,
                            float* __restrict__ out) {
    __shared__ float vals[CAP];          // 8 KB
    __shared__ float xcl[Kt][130];       // 15.6 KB, padded rows
    __shared__ float fl[CO * LOUT];      // 3.3 KB
    __shared__ float pz[8][Hd];          // 4 KB
    __shared__ float z[Hd];
    __shared__ int selS[Kt];
    int b = blockIdx.x, tid = threadIdx.x;

    int s0 = bstart[b], s1 = bstart[b + 1];
    int n = s1 - s0;
    int nc = n < CAP ? n : CAP;
    if (tid < Kt) selS[tid] = -1;
    // lastcol for own batch from compact hw127 (identical 8/4/1 tree)
    float b2l = b2[127];
    for (int j = tid; j < nc; j += 1024) {
        int node = s0 + j;
        float a0 = hw127[node];
        float a1 = 0.f, a2 = 0.f, a3 = 0.f, a4 = 0.f, a5 = 0.f, a6 = 0.f, a7 = 0.f;
        int e0 = row_ptr[node], e1 = row_ptr[node + 1];
        int e = e0;
        for (; e + 7 < e1; e += 8) {
            int q0 = __builtin_nontemporal_load(csr_src + e);
            int q1 = __builtin_nontemporal_load(csr_src + e + 1);
            int q2 = __builtin_nontemporal_load(csr_src + e + 2);
            int q3 = __builtin_nontemporal_load(csr_src + e + 3);
            int q4 = __builtin_nontemporal_load(csr_src + e + 4);
            int q5 = __builtin_nontemporal_load(csr_src + e + 5);
            int q6 = __builtin_nontemporal_load(csr_src + e + 6);
            int q7 = __builtin_nontemporal_load(csr_src + e + 7);
            a0 += hw127[q0];
            a1 += hw127[q1];
            a2 += hw127[q2];
            a3 += hw127[q3];
            a4 += hw127[q4];
            a5 += hw127[q5];
            a6 += hw127[q6];
            a7 += hw127[q7];
        }
        if (e + 3 < e1) {
            int q0 = __builtin_nontemporal_load(csr_src + e);
            int q1 = __builtin_nontemporal_load(csr_src + e + 1);
            int q2 = __builtin_nontemporal_load(csr_src + e + 2);
            int q3 = __builtin_nontemporal_load(csr_src + e + 3);
            a4 += hw127[q0];
            a5 += hw127[q1];
            a6 += hw127[q2];
            a7 += hw127[q3];
            e += 4;
        }
        for (; e < e1; ++e) {
            int q0 = __builtin_nontemporal_load(csr_src + e);
            a0 += hw127[q0];
        }
        float acc = ((a0 + a1) + (a2 + a3)) + ((a4 + a5) + (a6 + a7));
        vals[j] = fmaxf(fmaf(dinv[node], acc, b2l), 0.f);
    }
    __syncthreads();

    // rank pass (descending value, tie: smaller index)
    for (int j = tid; j < nc; j += 1024) {
        float vj = vals[j];
        int rank = 0;
        for (int i = 0; i < nc; ++i) {          // i wave-uniform -> LDS broadcast
            float vi = vals[i];
            rank += (vi > vj || (vi == vj && i < j)) ? 1 : 0;
        }
        if (rank < Kt) selS[rank] = s0 + j;
    }
    __syncthreads();

    // selective aggregation: one wave per selected node, identical tree to agg
    int wv = tid >> 6, lane = tid & 63;
    const v2f* hw2 = (const v2f*)hw;
    v2f bv = ((const v2f*)b2)[lane];
    for (int t = wv; t < Kt; t += 16) {
        int s = selS[t];
        v2f o = (v2f)0.f;
        if (s >= 0) {
            v2f a0 = hw2[(size_t)s * 64 + lane];
            v2f a1 = 0.f, a2 = 0.f, a3 = 0.f;
            v2f a4 = 0.f, a5 = 0.f, a6 = 0.f, a7 = 0.f;
            int e0 = row_ptr[s], e1 = row_ptr[s + 1];
            int e = e0;
            for (; e + 7 < e1; e += 8) {
                int q0 = __builtin_nontemporal_load(csr_src + e);
                int q1 = __builtin_nontemporal_load(csr_src + e + 1);
                int q2 = __builtin_nontemporal_load(csr_src + e + 2);
                int q3 = __builtin_nontemporal_load(csr_src + e + 3);
                int q4 = __builtin_nontemporal_load(csr_src + e + 4);
                int q5 = __builtin_nontemporal_load(csr_src + e + 5);
                int q6 = __builtin_nontemporal_load(csr_src + e + 6);
                int q7 = __builtin_nontemporal_load(csr_src + e + 7);
                a0 += hw2[(size_t)q0 * 64 + lane];
                a1 += hw2[(size_t)q1 * 64 + lane];
                a2 += hw2[(size_t)q2 * 64 + lane];
                a3 += hw2[(size_t)q3 * 64 + lane];
                a4 += hw2[(size_t)q4 * 64 + lane];
                a5 += hw2[(size_t)q5 * 64 + lane];
                a6 += hw2[(size_t)q6 * 64 + lane];
                a7 += hw2[(size_t)q7 * 64 + lane];
            }
            if (e + 3 < e1) {
                int q0 = __builtin_nontemporal_load(csr_src + e);
                int q1 = __builtin_nontemporal_load(csr_src + e + 1);
                int q2 = __builtin_nontemporal_load(csr_src + e + 2);
                int q3 = __builtin_nontemporal_load(csr_src + e + 3);
                a4 += hw2[(size_t)q0 * 64 + lane];
                a5 += hw2[(size_t)q1 * 64 + lane];
                a6 += hw2[(size_t)q2 * 64 + lane];
                a7 += hw2[(size_t)q3 * 64 + lane];
                e += 4;
            }
            for (; e < e1; ++e) {
                int q0 = __builtin_nontemporal_load(csr_src + e);
                a0 += hw2[(size_t)q0 * 64 + lane];
            }
            v2f acc = ((a0 + a1) + (a2 + a3)) + ((a4 + a5) + (a6 + a7));
            float d = dinv[s];
            o.x = fmaxf(fmaf(d, acc.x, bv.x), 0.f);
            o.y = fmaxf(fmaf(d, acc.y, bv.y), 0.f);
        }
        xcl[t][lane * 2] = o.x;
        xcl[t][lane * 2 + 1] = o.y;
    }
    __syncthreads();
    if (tid < CO * LOUT) {
        int o = tid / LOUT, t = tid - o * LOUT;
        float acc = conv_b[o];
#pragma unroll
        for (int k = 0; k < KW; ++k) {
            const float* xr = &xcl[t + k][0];
            const float* wr = wT2 + ((size_t)o * KW + k) * Hd;
#pragma unroll 8
            for (int c4 = 0; c4 < 32; ++c4) {
                float2 xa = *(const float2*)(xr + c4 * 4);
                float2 xb = *(const float2*)(xr + c4 * 4 + 2);
                float4 wv2 = *(const float4*)(wr + c4 * 4);
                acc = fmaf(xa.x, wv2.x, acc);
                acc = fmaf(xa.y, wv2.y, acc);
                acc = fmaf(xb.x, wv2.z, acc);
                acc = fmaf(xb.y, wv2.w, acc);
            }
        }
        fl[tid] = fmaxf(acc, 0.f);
    }
    __syncthreads();
    int hh = tid & 127, chunk = tid >> 7;
    int m0 = chunk * 104;
    float acc = 0.f;
    const float* lw = l1w + (size_t)m0 * Hd + hh;
#pragma unroll 8
    for (int m = 0; m < 104; ++m)
        acc = fmaf(fl[m0 + m], lw[(size_t)m * Hd], acc);
    pz[chunk][hh] = acc;
    __syncthreads();
    if (tid < Hd) {
        float a = l1b[tid];
#pragma unroll
        for (int q = 0; q < 8; ++q) a += pz[q][tid];
        z[tid] = fmaxf(a, 0.f);
    }
    __syncthreads();
    if (tid < 10) {
        float a2 = l2b[tid];
        for (int j = 0; j < Hd; ++j)
            a2 = fmaf(z[j], l2w[j * 10 + tid], a2);
        out[b * 10 + tid] = a2;
    }
}

extern "C" void kernel_launch(void* const* d_in, const int* in_sizes, int n_in,
                              void* d_out, int out_size, void* d_ws, size_t ws_size,
                              hipStream_t stream) {
    const float* x      = (const float*)d_in[0];
    const int*   ei     = (const int*)d_in[1];
    const int*   batch  = (const int*)d_in[2];
    const float* W0     = (const float*)d_in[3];
    const float* b0     = (const float*)d_in[4];
    const float* W1     = (const float*)d_in[5];
    const float* b1     = (const float*)d_in[6];
    const float* W2     = (const float*)d_in[7];
    const float* b2     = (const float*)d_in[8];
    const float* conv_w = (const float*)d_in[9];
    const float* conv_b = (const float*)d_in[10];
    const float* l1w    = (const float*)d_in[11];
    const float* l1b    = (const float*)d_in[12];
    const float* l2w    = (const float*)d_in[13];
    const float* l2b    = (const float*)d_in[14];
    float* out = (float*)d_out;

    // workspace layout — deg_i, cnt, bstart contiguous for one 0xFF memset
    int* wsI = (int*)d_ws;
    size_t off = 0;
    int*   deg_i   = wsI + off; off += Nn;
    int*   cnt     = wsI + off; off += Nn;
    int*   bstart  = wsI + off; off += 132;
    int*   row_ptr = wsI + off; off += 50004;
    float* dinv    = (float*)(wsI + off); off += Nn;
    int*   csr_src = wsI + off; off += Ee;
    off = (off + 3) & ~(size_t)3;        // 16B align
    ushort* Bph  = (ushort*)(wsI + off); off += 3 * 16384 / 2;   // packed W split hi
    ushort* Bpm  = (ushort*)(wsI + off); off += 3 * 16384 / 2;   // packed W split mid
    ushort* Bpl  = (ushort*)(wsI + off); off += 3 * 16384 / 2;   // packed W split lo
    float* hw    = (float*)(wsI + off); off += (size_t)Nn * Hd;
    float* hbuf  = (float*)(wsI + off); off += (size_t)Nn * Hd;
    float* wT2   = (float*)(wsI + off); off += CO * KW * Hd;
    float* hw127 = (float*)(wsI + off); off += Nn;

    // 1. set deg_i/cnt to -1, bstart to -1 sentinel (one DMA memset)
    hipMemsetAsync(deg_i, 0xFF, (size_t)(Nn + Nn + 132) * 4, stream);
    // 2. degree histogram + batch starts + W pack (one dispatch)
    countpack_kernel<<<(Ee + 255) / 256, 256, 0, stream>>>(ei, batch, deg_i, bstart,
        conv_w, wT2, W0, W1, W2, Bph, Bpm, Bpl);
    // 3. single-dispatch scan: direct offset sum + local scan + dinv + bstart fix
    scanBC2_kernel<<<SCB, 256, 0, stream>>>(deg_i, row_ptr, dinv, bstart);
    // 4. layer-0 matmul merged with CSR fill (independent work)
    dim3 aggGrid((Nn + 3) / 4);
    mmxfill_kernel<<<MMB + (Ee + 255) / 256, 256, 0, stream>>>(x, Bph, Bpm, Bpl,
        dinv, hw, hw127, ei, row_ptr, cnt, csr_src);
    agg_kernel<<<aggGrid, 256, 0, stream>>>(hw, row_ptr, csr_src, dinv, b0, hbuf);
    // 5. layers 1,2 (layer-2 matmul also emits compact ranking column hw127)
    mmx_kernel<<<MMB, 256, 0, stream>>>(hbuf, Bph + 16384, Bpm + 16384, Bpl + 16384,
        dinv, hw, hw127);
    agg_kernel<<<aggGrid, 256, 0, stream>>>(hw, row_ptr, csr_src, dinv, b1, hbuf);
    mmx_kernel<<<MMB, 256, 0, stream>>>(hbuf, Bph + 32768, Bpm + 32768, Bpl + 32768,
        dinv, hw, hw127);
    // 6. fused tail: lastcol(hw127) + rank-topk + selective agg + conv + lin1 + lin2
    tail_kernel<<<Bg, 1024, 0, stream>>>(hw, hw127, bstart, row_ptr, csr_src, dinv, b2,
                                         wT2, conv_b, l1w, l1b, l2w, l2b, out);
}